// Round 13
// baseline (234.464 us; speedup 1.0000x reference)
//
#include <hip/hip_runtime.h>
#include <hip/hip_bf16.h>
#include <math.h>

#define S_LEN 2048
#define DIM   1024
#define NH    16
#define NKVH  4
#define HD    64
#define KVDIM 256

typedef __hip_bfloat16 bf16;
typedef __attribute__((ext_vector_type(8))) short short8;   // 8 bf16 (4 VGPRs)
typedef __attribute__((ext_vector_type(4))) float f32x4;

__device__ __forceinline__ short bfbits(float v) {
    bf16 t = __float2bfloat16(v);
    return *(short*)&t;
}
__device__ __forceinline__ short8 pack8(float4 a, float4 b) {
    short8 r;
    r[0] = bfbits(a.x); r[1] = bfbits(a.y); r[2] = bfbits(a.z); r[3] = bfbits(a.w);
    r[4] = bfbits(b.x); r[5] = bfbits(b.y); r[6] = bfbits(b.z); r[7] = bfbits(b.w);
    return r;
}

// ---------------------------------------------------------------------------
// bf16 MFMA GEMM, fused fp32->bf16 staging cast (template per operand).
// C[M,N] = A[M,K]*B[N,K]^T, fp32 out. 64x64 tile, BK=64, 4 waves.
// ---------------------------------------------------------------------------
template <bool AF32, bool BF32>
__device__ __forceinline__ void gemm_core(
    const void* __restrict__ Av, const void* __restrict__ Bv,
    float* __restrict__ C, int bm, int bn, int N, int K) {
    __shared__ short As[64 * 72];
    __shared__ short Bs[64 * 72];
    const int tid  = threadIdx.x;
    const int w    = tid >> 6;
    const int lane = tid & 63;
    const int quad = lane >> 4;
    const int lm   = lane & 15;
    const int row  = tid >> 2;
    const int kc   = (tid & 3) * 16;
    f32x4 acc[4] = {};
    const int aoff = (w * 16 + lm) * 72 + quad * 8;
    const int boff = lm * 72 + quad * 8;
    for (int k0 = 0; k0 < K; k0 += 64) {
        short8 sa0, sa1, sb0, sb1;
        if constexpr (AF32) {
            const float* ap = (const float*)Av + (size_t)(bm + row) * K + kc + k0;
            sa0 = pack8(*(const float4*)ap,       *(const float4*)(ap + 4));
            sa1 = pack8(*(const float4*)(ap + 8), *(const float4*)(ap + 12));
        } else {
            const bf16* ap = (const bf16*)Av + (size_t)(bm + row) * K + kc + k0;
            sa0 = *(const short8*)ap;
            sa1 = *(const short8*)(ap + 8);
        }
        if constexpr (BF32) {
            const float* bp = (const float*)Bv + (size_t)(bn + row) * K + kc + k0;
            sb0 = pack8(*(const float4*)bp,       *(const float4*)(bp + 4));
            sb1 = pack8(*(const float4*)(bp + 8), *(const float4*)(bp + 12));
        } else {
            const bf16* bp = (const bf16*)Bv + (size_t)(bn + row) * K + kc + k0;
            sb0 = *(const short8*)bp;
            sb1 = *(const short8*)(bp + 8);
        }
        *(short8*)&As[row * 72 + kc]     = sa0;
        *(short8*)&As[row * 72 + kc + 8] = sa1;
        *(short8*)&Bs[row * 72 + kc]     = sb0;
        *(short8*)&Bs[row * 72 + kc + 8] = sb1;
        __syncthreads();
        short8 a0 = *(const short8*)&As[aoff];
        short8 a1 = *(const short8*)&As[aoff + 32];
        #pragma unroll
        for (int t = 0; t < 4; ++t) {
            short8 b0 = *(const short8*)&Bs[boff + t * 16 * 72];
            short8 b1 = *(const short8*)&Bs[boff + t * 16 * 72 + 32];
            acc[t] = __builtin_amdgcn_mfma_f32_16x16x32_bf16(a0, b0, acc[t], 0, 0, 0);
            acc[t] = __builtin_amdgcn_mfma_f32_16x16x32_bf16(a1, b1, acc[t], 0, 0, 0);
        }
        __syncthreads();
    }
    const int r0 = bm + w * 16 + quad * 4;
    #pragma unroll
    for (int t = 0; t < 4; ++t) {
        const int col = bn + t * 16 + lm;
        #pragma unroll
        for (int i = 0; i < 4; ++i)
            C[(size_t)(r0 + i) * N + col] = acc[t][i];
    }
}

__global__ __launch_bounds__(256) void gemm_qproj(
    const float* __restrict__ x, const float* __restrict__ Wq,
    float* __restrict__ C) {
    gemm_core<true, true>(x, Wq, C, blockIdx.y * 64, blockIdx.x * 64, DIM, DIM);
}

__global__ __launch_bounds__(256) void gemm_kvg(
    const float* __restrict__ x, const float* __restrict__ Wk,
    const float* __restrict__ Wv, const float* __restrict__ Wg,
    float* __restrict__ KVG) {
    const int wsel = blockIdx.x >> 2;
    const float* B = (wsel == 0) ? Wk : (wsel == 1) ? Wv : Wg;
    float* C = KVG + (size_t)wsel * S_LEN * KVDIM;
    gemm_core<true, true>(x, B, C, blockIdx.y * 64, (blockIdx.x & 3) * 64, KVDIM, DIM);
}

__global__ __launch_bounds__(256) void gemm_out(
    const bf16* __restrict__ Yb, const float* __restrict__ Wo,
    float* __restrict__ C) {
    gemm_core<false, true>(Yb, Wo, C, blockIdx.y * 64, blockIdx.x * 64, DIM, DIM);
}

// ---------------------------------------------------------------------------
// Postproc: fp32 in -> bf16 out (verified round 12)
// ---------------------------------------------------------------------------
__device__ __forceinline__ void rms_rotary_b(
    const float* __restrict__ p, bf16* __restrict__ pb, int s, int lane, float gain) {
    float x = p[lane];
    float ss = x * x;
    #pragma unroll
    for (int o = 32; o > 0; o >>= 1) ss += __shfl_xor(ss, o);
    float n = x * rsqrtf(ss * (1.0f/64.0f) + 1.1920928955078125e-7f);
    float other = __shfl_xor(n, 32);
    int i = lane & 31;
    float af  = (float)(((double)(2*i) / 64.0) * 3.14159265358979323846);
    float ang = (float)s * af;
    float radius = 1.0f / (1.0f + 0.01f * (float)s);
    float c  = radius * (float)cos((double)ang);
    float sn = radius * (float)sin((double)ang);
    float out = n * c + ((lane < 32) ? other * sn : -other * sn);
    pb[lane] = __float2bfloat16(out * gain);
}

__global__ __launch_bounds__(64) void postproc_b(
    const float* __restrict__ Qp, const float* __restrict__ Kp,
    const float* __restrict__ Vp, const float* __restrict__ Gp,
    bf16* __restrict__ Qb, bf16* __restrict__ Kb, bf16* __restrict__ Vb,
    const float* __restrict__ qgain) {
    const int s = blockIdx.x;
    const int unit = blockIdx.y;
    const int lane = threadIdx.x;
    if (unit < NH) {
        rms_rotary_b(Qp + (size_t)s * DIM + unit * HD,
                     Qb + (size_t)s * DIM + unit * HD, s, lane, qgain[unit]);
    } else if (unit < NH + NKVH) {
        rms_rotary_b(Kp + (size_t)s * KVDIM + (unit - NH) * HD,
                     Kb + (size_t)s * KVDIM + (unit - NH) * HD, s, lane, 1.0f);
    } else {
        const int h = unit - NH - NKVH;
        const float* v = Vp + (size_t)s * KVDIM + h * HD;
        const float* g = Gp + (size_t)s * KVDIM + h * HD;
        bf16* vb = Vb + (size_t)s * KVDIM + h * HD;
        float gv = g[lane];
        vb[lane] = __float2bfloat16(v[lane] / (1.0f + __expf(-gv)));
    }
}

// ---------------------------------------------------------------------------
// One-shot global V transpose: VT[(kvh*64+dim)*S + key] = Vb[key][kvh*64+dim].
// 64-key x 64-dim LDS tile per (s-block, kvh). Reused by 128 attn blocks.
// ---------------------------------------------------------------------------
__global__ __launch_bounds__(256) void vtrans(
    const bf16* __restrict__ Vb, bf16* __restrict__ VT) {
    __shared__ short T[64 * 72];
    const int s0  = blockIdx.x * 64;
    const int kvh = blockIdx.y;
    const int tid = threadIdx.x;
    {
        const int key = tid >> 2, dc = tid & 3;
        const bf16* p = Vb + (size_t)(s0 + key) * KVDIM + kvh * 64 + dc * 16;
        *(short8*)&T[key * 72 + dc * 16]     = *(const short8*)p;
        *(short8*)&T[key * 72 + dc * 16 + 8] = *(const short8*)(p + 8);
    }
    __syncthreads();
    {
        const int dim = tid >> 2, kc = tid & 3;
        short8 r0, r1;
        #pragma unroll
        for (int i = 0; i < 8; ++i) r0[i] = T[(kc * 16 + i) * 72 + dim];
        #pragma unroll
        for (int i = 0; i < 8; ++i) r1[i] = T[(kc * 16 + 8 + i) * 72 + dim];
        bf16* o = VT + (size_t)(kvh * 64 + dim) * S_LEN + s0 + kc * 16;
        *(short8*)o       = r0;
        *(short8*)(o + 8) = r1;
    }
}

// ---------------------------------------------------------------------------
// MFMA flash attention v2: K and V^T B-frags straight from global; only P
// round-trips LDS (C->A layout, single buffer/wave — one instruction stream
// makes WAR across iterations safe). No-max softmax (bounded scores,
// verified R11/R12); O accumulates in MFMA C-regs. 8 blocks/CU.
// ---------------------------------------------------------------------------
__global__ __launch_bounds__(256, 8) void attn_mfma(
    const bf16* __restrict__ Qb, const bf16* __restrict__ Kb,
    const bf16* __restrict__ VT, float* __restrict__ Ao) {
    __shared__ short plds[4 * 640];       // 4 waves x (16 rows x 40 shorts)
    const int id   = blockIdx.x;
    const int qt   = 31 - (id >> 5);
    const int hh   = id & 31;
    const int h    = hh >> 1;
    const int half = hh & 1;
    const int kvh  = h >> 2;
    const int tid  = threadIdx.x;
    const int w    = tid >> 6;
    const int lane = tid & 63;
    const int quad = lane >> 4;
    const int m    = lane & 15;
    short* PW = &plds[w * 640];
    bf16* PWb = (bf16*)PW;

    const int qrow = qt * 64 + w * 16 + m;
    short8 qf = *(const short8*)(Qb + (size_t)qrow * DIM + h * HD + half * 32 + quad * 8);

    f32x4 o0 = {}, o1 = {};
    float lpart[4] = {0.f, 0.f, 0.f, 0.f};
    const float scale = 0.17677669529663687f;   // 1/sqrt(32)
    const int rbase = qt * 64 + w * 16 + quad * 4;
    const int nkt = ((qt * 64 + w * 16 + 15) >> 5) + 1;   // per-wave early exit
    const size_t kroff  = kvh * HD + half * 32 + quad * 8;
    const bf16* vt0 = VT + (size_t)(kvh * 64 + half * 32 + m)      * S_LEN + quad * 8;
    const bf16* vt1 = VT + (size_t)(kvh * 64 + half * 32 + 16 + m) * S_LEN + quad * 8;

    for (int kb = 0; kb < nkt; ++kb) {
        // QK^T: K B-frags from global (n=key, k=dim)
        short8 kf0 = *(const short8*)(Kb + (size_t)(kb * 32 + m)      * KVDIM + kroff);
        short8 kf1 = *(const short8*)(Kb + (size_t)(kb * 32 + 16 + m) * KVDIM + kroff);
        f32x4 s0 = {}, s1 = {};
        s0 = __builtin_amdgcn_mfma_f32_16x16x32_bf16(qf, kf0, s0, 0, 0, 0);
        s1 = __builtin_amdgcn_mfma_f32_16x16x32_bf16(qf, kf1, s1, 0, 0, 0);
        // V^T B-frags from global (n=dim, k=key)
        short8 vtf0 = *(const short8*)(vt0 + kb * 32);
        short8 vtf1 = *(const short8*)(vt1 + kb * 32);
        // exp + causal mask (fp32, no max-sub) -> P bf16 in C-layout position
        const int kg = kb * 32 + m;
        #pragma unroll
        for (int r = 0; r < 4; ++r) {
            const int rg = rbase + r;
            const float p0 = (kg > rg)      ? 0.f : __expf(s0[r] * scale);
            const float p1 = (kg + 16 > rg) ? 0.f : __expf(s1[r] * scale);
            lpart[r] += p0 + p1;
            PWb[(quad * 4 + r) * 40 + m]      = __float2bfloat16(p0);
            PWb[(quad * 4 + r) * 40 + 16 + m] = __float2bfloat16(p1);
        }
        asm volatile("s_waitcnt lgkmcnt(0)" ::: "memory");
        // P A-frag; PV accumulates into O C-regs
        short8 pf = *(const short8*)&PW[m * 40 + quad * 8];
        o0 = __builtin_amdgcn_mfma_f32_16x16x32_bf16(pf, vtf0, o0, 0, 0, 0);
        o1 = __builtin_amdgcn_mfma_f32_16x16x32_bf16(pf, vtf1, o1, 0, 0, 0);
    }

    #pragma unroll
    for (int r = 0; r < 4; ++r) {
        float v = lpart[r];
        v += __shfl_xor(v, 1);
        v += __shfl_xor(v, 2);
        v += __shfl_xor(v, 4);
        v += __shfl_xor(v, 8);
        lpart[r] = 1.f / v;
    }
    #pragma unroll
    for (int r = 0; r < 4; ++r) {
        float* op = Ao + (size_t)(rbase + r) * DIM + h * HD + half * 32;
        op[m]      = o0[r] * lpart[r];
        op[16 + m] = o1[r] * lpart[r];
    }
}

// ---------------------------------------------------------------------------
// Combine -> bf16 Y (verified)
// ---------------------------------------------------------------------------
__global__ __launch_bounds__(256) void combine_kernel(
    const float* __restrict__ A, const float* __restrict__ lambda_p,
    bf16* __restrict__ Y) {
    const int idx = blockIdx.x * 256 + threadIdx.x;
    const int c = idx & (DIM - 1);
    const int s = idx >> 10;
    const int hh = c >> 6;
    const int d = c & 63;
    const float* base = A + (size_t)s * DIM + hh * HD;
    const float lam = lambda_p[hh];
    float y;
    if (d < 32) y = base[d]      - lam * base[d + 32];
    else        y = base[d - 32] + lam * base[d];
    Y[idx] = __float2bfloat16(y);
}

// ---------------------------------------------------------------------------
// Workspace (29 MB):
//  0-8   Qp fp32 (dead after postproc) -> Yb bf16 overlays
//  8-14  KVG fp32 (dead after postproc)
//  14-22 Ao fp32
//  22-26 Qb bf16 | 26-27 Kb | 27-28 Vb | 28-29 VT
// ---------------------------------------------------------------------------
extern "C" void kernel_launch(void* const* d_in, const int* in_sizes, int n_in,
                              void* d_out, int out_size, void* d_ws, size_t ws_size,
                              hipStream_t stream) {
    const float* x  = (const float*)d_in[0];
    const float* Wq = (const float*)d_in[1];
    const float* Wk = (const float*)d_in[2];
    const float* Wv = (const float*)d_in[3];
    const float* Wg = (const float*)d_in[4];
    const float* Wo = (const float*)d_in[5];
    const float* qg = (const float*)d_in[6];
    const float* lp = (const float*)d_in[7];
    float* out = (float*)d_out;

    char* ws = (char*)d_ws;
    float* Qp  = (float*)(ws);
    float* KVG = (float*)(ws + (8u  << 20));
    float* Kp  = KVG;
    float* Vp  = KVG + (size_t)S_LEN * KVDIM;
    float* Gp  = KVG + (size_t)2 * S_LEN * KVDIM;
    float* Ao  = (float*)(ws + (14u << 20));
    bf16* Qb   = (bf16*)(ws + (22u << 20));
    bf16* Kb   = (bf16*)(ws + (26u << 20));
    bf16* Vb   = (bf16*)(ws + (27u << 20));
    bf16* VTb  = (bf16*)(ws + (28u << 20));
    bf16* Yb   = (bf16*)ws;                  // overlays dead Qp

    // 1. MFMA projections, fp32 inputs cast in staging
    gemm_qproj<<<dim3(DIM/64, S_LEN/64), 256, 0, stream>>>(x, Wq, Qp);
    gemm_kvg<<<dim3(12, S_LEN/64), 256, 0, stream>>>(x, Wk, Wv, Wg, KVG);

    // 2. RMSNorm + rotary + gate -> bf16 Q/K/V
    postproc_b<<<dim3(S_LEN, NH + 2*NKVH), 64, 0, stream>>>(
        Qp, Kp, Vp, Gp, Qb, Kb, Vb, qg);

    // 3. One-shot V transpose (per kvh), then MFMA flash attention
    vtrans<<<dim3(S_LEN/64, NKVH), 256, 0, stream>>>(Vb, VTb);
    attn_mfma<<<1024, 256, 0, stream>>>(Qb, Kb, VTb, Ao);

    // 4. Lambda combine -> bf16 Y (overlays dead Qp)
    combine_kernel<<<S_LEN * DIM / 256, 256, 0, stream>>>(Ao, lp, Yb);

    // 5. MFMA output projection (Wo cast in staging) -> fp32 out
    gemm_out<<<dim3(DIM/64, S_LEN/64), 256, 0, stream>>>(Yb, Wo, out);
}

// Round 14
// 172.873 us; speedup vs baseline: 1.3563x; 1.3563x over previous
//
#include <hip/hip_runtime.h>
#include <hip/hip_bf16.h>
#include <math.h>

#define S_LEN 2048
#define DIM   1024
#define NH    16
#define NKVH  4
#define HD    64
#define KVDIM 256

typedef __hip_bfloat16 bf16;
typedef __attribute__((ext_vector_type(8))) short short8;   // 8 bf16 (4 VGPRs)
typedef __attribute__((ext_vector_type(4))) float f32x4;

// ---------------------------------------------------------------------------
// One-dispatch fp32 -> bf16 cast of all six inputs (grid.y = which)
// ---------------------------------------------------------------------------
__global__ __launch_bounds__(256) void cast6(
    const float* __restrict__ x,  const float* __restrict__ Wq,
    const float* __restrict__ Wk, const float* __restrict__ Wv,
    const float* __restrict__ Wg, const float* __restrict__ Wo,
    bf16* __restrict__ xb,  bf16* __restrict__ Wqb,
    bf16* __restrict__ Wkb, bf16* __restrict__ Wvb,
    bf16* __restrict__ Wgb, bf16* __restrict__ Wob) {
    const float* s; bf16* d; int n;
    switch (blockIdx.y) {
        case 0: s = x;  d = xb;  n = S_LEN * DIM; break;
        case 1: s = Wq; d = Wqb; n = DIM * DIM;   break;
        case 2: s = Wk; d = Wkb; n = KVDIM * DIM; break;
        case 3: s = Wv; d = Wvb; n = KVDIM * DIM; break;
        case 4: s = Wg; d = Wgb; n = KVDIM * DIM; break;
        default: s = Wo; d = Wob; n = DIM * DIM;  break;
    }
    for (int i = (blockIdx.x * 256 + threadIdx.x) * 4; i < n; i += gridDim.x * 1024) {
        float4 v = *(const float4*)(s + i);
        d[i]     = __float2bfloat16(v.x);
        d[i + 1] = __float2bfloat16(v.y);
        d[i + 2] = __float2bfloat16(v.z);
        d[i + 3] = __float2bfloat16(v.w);
    }
}

// ---------------------------------------------------------------------------
// bf16 MFMA GEMM core (verified R11/R12): C[M,N] = A[M,K]*B[N,K]^T, fp32 out.
// ---------------------------------------------------------------------------
__device__ __forceinline__ void gemm_core(
    const bf16* __restrict__ A, const bf16* __restrict__ B,
    float* __restrict__ C, int bm, int bn, int N, int K) {
    __shared__ short As[64 * 72];
    __shared__ short Bs[64 * 72];
    const int tid  = threadIdx.x;
    const int w    = tid >> 6;
    const int lane = tid & 63;
    const int quad = lane >> 4;
    const int lm   = lane & 15;
    const int row  = tid >> 2;
    const int kc   = (tid & 3) * 16;
    const bf16* ap = A + (size_t)(bm + row) * K + kc;
    const bf16* bp = B + (size_t)(bn + row) * K + kc;
    f32x4 acc[4] = {};
    const int aoff = (w * 16 + lm) * 72 + quad * 8;
    const int boff = lm * 72 + quad * 8;
    for (int k0 = 0; k0 < K; k0 += 64) {
        uint4 av0 = *(const uint4*)(ap + k0);
        uint4 av1 = *(const uint4*)(ap + k0 + 8);
        uint4 bv0 = *(const uint4*)(bp + k0);
        uint4 bv1 = *(const uint4*)(bp + k0 + 8);
        *(uint4*)&As[row * 72 + kc]     = av0;
        *(uint4*)&As[row * 72 + kc + 8] = av1;
        *(uint4*)&Bs[row * 72 + kc]     = bv0;
        *(uint4*)&Bs[row * 72 + kc + 8] = bv1;
        __syncthreads();
        short8 a0 = *(const short8*)&As[aoff];
        short8 a1 = *(const short8*)&As[aoff + 32];
        #pragma unroll
        for (int t = 0; t < 4; ++t) {
            short8 b0 = *(const short8*)&Bs[boff + t * 16 * 72];
            short8 b1 = *(const short8*)&Bs[boff + t * 16 * 72 + 32];
            acc[t] = __builtin_amdgcn_mfma_f32_16x16x32_bf16(a0, b0, acc[t], 0, 0, 0);
            acc[t] = __builtin_amdgcn_mfma_f32_16x16x32_bf16(a1, b1, acc[t], 0, 0, 0);
        }
        __syncthreads();
    }
    const int r0 = bm + w * 16 + quad * 4;
    #pragma unroll
    for (int t = 0; t < 4; ++t) {
        const int col = bn + t * 16 + lm;
        #pragma unroll
        for (int i = 0; i < 4; ++i)
            C[(size_t)(r0 + i) * N + col] = acc[t][i];
    }
}

// Fused Q+K+V+G projection: one dispatch, N_total=1792, grid (28, 32).
__global__ __launch_bounds__(256) void gemm_qkvg(
    const bf16* __restrict__ xb, const bf16* __restrict__ Wqb,
    const bf16* __restrict__ Wkb, const bf16* __restrict__ Wvb,
    const bf16* __restrict__ Wgb, float* __restrict__ Qp,
    float* __restrict__ KVG) {
    const int c0 = blockIdx.x * 64;
    const bf16* B; float* C; int bn, N;
    if (c0 < DIM) { B = Wqb; C = Qp; bn = c0; N = DIM; }
    else {
        const int t = c0 - DIM;
        const int wsel = t >> 8;
        B = (wsel == 0) ? Wkb : (wsel == 1) ? Wvb : Wgb;
        C = KVG + (size_t)wsel * S_LEN * KVDIM;
        bn = t & 255; N = KVDIM;
    }
    gemm_core(xb, B, C, blockIdx.y * 64, bn, N, DIM);
}

__global__ __launch_bounds__(256) void gemm_out(
    const bf16* __restrict__ Yb, const bf16* __restrict__ Wob,
    float* __restrict__ C) {
    gemm_core(Yb, Wob, C, blockIdx.y * 64, blockIdx.x * 64, DIM, DIM);
}

// ---------------------------------------------------------------------------
// Postproc -> Qb (row-major bf16) and B-fragment-PACKED Kpk/Vpk.
// Kpk element (key s, kvh, dl): half=dl>>5, d32=dl&31, quad=d32>>3, e=d32&7,
//   kb=s>>5, g=(s&31)>>4, m=s&15  ->  ((((kvh*2+half)*64+kb)*2+g)*64
//                                      + quad*16+m)*8 + e
// Vpk element (key s, kvh, dl): g=d32>>4, m=d32&15, quad=(s&31)>>3, j=s&7
//   -> ((((kvh*2+half)*64+kb)*2+g)*64 + quad*16+m)*8 + j
// Attn then loads every K/V fragment as one contiguous 1 KB wave read.
// ---------------------------------------------------------------------------
__device__ __forceinline__ float rms_rot_val(
    const float* __restrict__ p, int s, int lane, float gain) {
    float x = p[lane];
    float ss = x * x;
    #pragma unroll
    for (int o = 32; o > 0; o >>= 1) ss += __shfl_xor(ss, o);
    float n = x * rsqrtf(ss * (1.0f/64.0f) + 1.1920928955078125e-7f);
    float other = __shfl_xor(n, 32);
    int i = lane & 31;
    float af  = (float)(((double)(2*i) / 64.0) * 3.14159265358979323846);
    float ang = (float)s * af;
    float radius = 1.0f / (1.0f + 0.01f * (float)s);
    float c  = radius * (float)cos((double)ang);
    float sn = radius * (float)sin((double)ang);
    return (n * c + ((lane < 32) ? other * sn : -other * sn)) * gain;
}

__global__ __launch_bounds__(64) void postproc_pk(
    const float* __restrict__ Qp, const float* __restrict__ Kp,
    const float* __restrict__ Vp, const float* __restrict__ Gp,
    bf16* __restrict__ Qb, bf16* __restrict__ Kpk, bf16* __restrict__ Vpk,
    const float* __restrict__ qgain) {
    const int s = blockIdx.x;
    const int unit = blockIdx.y;
    const int lane = threadIdx.x;
    const int half = lane >> 5, d32 = lane & 31;
    const int kb = s >> 5;
    if (unit < NH) {
        float v = rms_rot_val(Qp + (size_t)s * DIM + unit * HD, s, lane, qgain[unit]);
        Qb[(size_t)s * DIM + unit * HD + lane] = __float2bfloat16(v);
    } else if (unit < NH + NKVH) {
        const int kvh = unit - NH;
        float v = rms_rot_val(Kp + (size_t)s * KVDIM + kvh * HD, s, lane, 1.0f);
        const size_t ki = (((((size_t)(kvh*2 + half)*64 + kb)*2 + ((s&31)>>4))*64)
                           + (d32>>3)*16 + (s&15))*8 + (d32&7);
        Kpk[ki] = __float2bfloat16(v);
    } else {
        const int kvh = unit - NH - NKVH;
        const float* v = Vp + (size_t)s * KVDIM + kvh * HD;
        const float* g = Gp + (size_t)s * KVDIM + kvh * HD;
        float gv = g[lane];
        float val = v[lane] / (1.0f + __expf(-gv));
        const size_t vi = (((((size_t)(kvh*2 + half)*64 + kb)*2 + (d32>>4))*64)
                           + ((s&31)>>3)*16 + (d32&15))*8 + (s&7);
        Vpk[vi] = __float2bfloat16(val);
    }
}

// ---------------------------------------------------------------------------
// MFMA flash attention v3: 1 wave per block, grid 4096 = (128 qtiles of 16
// rows, heavy first) x 32 head-halves. All K/V fragment loads are contiguous
// 1 KB wave reads from the packed layouts. No-max softmax (bounded scores,
// verified R11/R12); O accumulates in MFMA C-regs; P round-trips wave-private
// LDS (C->A layout).
// ---------------------------------------------------------------------------
__global__ __launch_bounds__(64, 4) void attn_mfma(
    const bf16* __restrict__ Qb, const bf16* __restrict__ Kpk,
    const bf16* __restrict__ Vpk, float* __restrict__ Ao) {
    __shared__ short PW[640];             // 16 rows x 40 shorts
    const int id    = blockIdx.x;
    const int qtile = 127 - (id >> 5);
    const int hh    = id & 31;
    const int h     = hh >> 1;
    const int half  = hh & 1;
    const int kvh   = h >> 2;
    const int lane  = threadIdx.x;
    const int quad  = lane >> 4;
    const int m     = lane & 15;
    bf16* PWb = (bf16*)PW;

    const int qrow = qtile * 16 + m;
    short8 qf = *(const short8*)(Qb + (size_t)qrow * DIM + h * HD + half * 32 + quad * 8);

    const bf16* kbase = Kpk + (size_t)(kvh * 2 + half) * 64 * 1024 + lane * 8;
    const bf16* vbase = Vpk + (size_t)(kvh * 2 + half) * 64 * 1024 + lane * 8;

    f32x4 o0 = {}, o1 = {};
    float lpart[4] = {0.f, 0.f, 0.f, 0.f};
    const float scale = 0.17677669529663687f;   // 1/sqrt(32)
    const int rbase = qtile * 16 + quad * 4;
    const int nkt = (qtile >> 1) + 1;

    for (int kb = 0; kb < nkt; ++kb) {
        short8 kf0 = *(const short8*)(kbase + kb * 1024);
        short8 kf1 = *(const short8*)(kbase + kb * 1024 + 512);
        f32x4 s0 = {}, s1 = {};
        s0 = __builtin_amdgcn_mfma_f32_16x16x32_bf16(qf, kf0, s0, 0, 0, 0);
        s1 = __builtin_amdgcn_mfma_f32_16x16x32_bf16(qf, kf1, s1, 0, 0, 0);
        short8 vtf0 = *(const short8*)(vbase + kb * 1024);
        short8 vtf1 = *(const short8*)(vbase + kb * 1024 + 512);
        const int kg = kb * 32 + m;
        #pragma unroll
        for (int r = 0; r < 4; ++r) {
            const int rg = rbase + r;
            const float p0 = (kg > rg)      ? 0.f : __expf(s0[r] * scale);
            const float p1 = (kg + 16 > rg) ? 0.f : __expf(s1[r] * scale);
            lpart[r] += p0 + p1;
            PWb[(quad * 4 + r) * 40 + m]      = __float2bfloat16(p0);
            PWb[(quad * 4 + r) * 40 + 16 + m] = __float2bfloat16(p1);
        }
        asm volatile("s_waitcnt lgkmcnt(0)" ::: "memory");
        short8 pf = *(const short8*)&PW[m * 40 + quad * 8];
        o0 = __builtin_amdgcn_mfma_f32_16x16x32_bf16(pf, vtf0, o0, 0, 0, 0);
        o1 = __builtin_amdgcn_mfma_f32_16x16x32_bf16(pf, vtf1, o1, 0, 0, 0);
    }

    #pragma unroll
    for (int r = 0; r < 4; ++r) {
        float v = lpart[r];
        v += __shfl_xor(v, 1);
        v += __shfl_xor(v, 2);
        v += __shfl_xor(v, 4);
        v += __shfl_xor(v, 8);
        lpart[r] = 1.f / v;
    }
    #pragma unroll
    for (int r = 0; r < 4; ++r) {
        float* op = Ao + (size_t)(rbase + r) * DIM + h * HD + half * 32;
        op[m]      = o0[r] * lpart[r];
        op[16 + m] = o1[r] * lpart[r];
    }
}

// ---------------------------------------------------------------------------
// Combine -> bf16 Y (verified)
// ---------------------------------------------------------------------------
__global__ __launch_bounds__(256) void combine_kernel(
    const float* __restrict__ A, const float* __restrict__ lambda_p,
    bf16* __restrict__ Y) {
    const int idx = blockIdx.x * 256 + threadIdx.x;
    const int c = idx & (DIM - 1);
    const int s = idx >> 10;
    const int hh = c >> 6;
    const int d = c & 63;
    const float* base = A + (size_t)s * DIM + hh * HD;
    const float lam = lambda_p[hh];
    float y;
    if (d < 32) y = base[d]      - lam * base[d + 32];
    else        y = base[d - 32] + lam * base[d];
    Y[idx] = __float2bfloat16(y);
}

// ---------------------------------------------------------------------------
// Workspace (31.5 MB):
//  0-8    Qp fp32 (dead after postproc) -> Yb bf16 overlays 0-4
//  8-14   KVG fp32 (Kp 8-10, Vp 10-12, Gp 12-14; dead after postproc)
//  14-22  Ao fp32
//  22-26  xb bf16 (dead after gemm_qkvg) -> Qb overlays
//  26-28  Wqb (dead after gemm) -> Kpk 26-27, Vpk 27-28 overlay
//  28-29.5 Wkb/Wvb/Wgb | 29.5-31.5 Wob (live till gemm_out)
// ---------------------------------------------------------------------------
extern "C" void kernel_launch(void* const* d_in, const int* in_sizes, int n_in,
                              void* d_out, int out_size, void* d_ws, size_t ws_size,
                              hipStream_t stream) {
    const float* x  = (const float*)d_in[0];
    const float* Wq = (const float*)d_in[1];
    const float* Wk = (const float*)d_in[2];
    const float* Wv = (const float*)d_in[3];
    const float* Wg = (const float*)d_in[4];
    const float* Wo = (const float*)d_in[5];
    const float* qg = (const float*)d_in[6];
    const float* lp = (const float*)d_in[7];
    float* out = (float*)d_out;

    char* ws = (char*)d_ws;
    float* Qp  = (float*)(ws);
    float* KVG = (float*)(ws + (8u  << 20));
    float* Kp  = KVG;
    float* Vp  = KVG + (size_t)S_LEN * KVDIM;
    float* Gp  = KVG + (size_t)2 * S_LEN * KVDIM;
    float* Ao  = (float*)(ws + (14u << 20));
    bf16* xb   = (bf16*)(ws + (22u << 20));
    bf16* Wqb  = (bf16*)(ws + (26u << 20));
    bf16* Wkb  = (bf16*)(ws + (28u << 20));
    bf16* Wvb  = (bf16*)(ws + (28u << 20) + (512u << 10));
    bf16* Wgb  = (bf16*)(ws + (29u << 20));
    bf16* Wob  = (bf16*)(ws + (29u << 20) + (512u << 10));
    bf16* Qb   = (bf16*)(ws + (22u << 20));  // overlays dead xb
    bf16* Kpk  = (bf16*)(ws + (26u << 20));  // overlays dead Wqb
    bf16* Vpk  = (bf16*)(ws + (27u << 20));
    bf16* Yb   = (bf16*)ws;                  // overlays dead Qp

    // 0. One-dispatch cast of all inputs to bf16
    cast6<<<dim3(512, 6), 256, 0, stream>>>(x, Wq, Wk, Wv, Wg, Wo,
                                            xb, Wqb, Wkb, Wvb, Wgb, Wob);

    // 1. Fused Q/K/V/G projection (one dispatch, 896 blocks)
    gemm_qkvg<<<dim3(28, S_LEN/64), 256, 0, stream>>>(xb, Wqb, Wkb, Wvb, Wgb, Qp, KVG);

    // 2. RMSNorm + rotary + gate -> Qb + packed Kpk/Vpk
    postproc_pk<<<dim3(S_LEN, NH + 2*NKVH), 64, 0, stream>>>(
        Qp, Kp, Vp, Gp, Qb, Kpk, Vpk, qg);

    // 3. MFMA flash attention (4096 single-wave blocks, coalesced frags)
    attn_mfma<<<4096, 64, 0, stream>>>(Qb, Kpk, Vpk, Ao);

    // 4. Lambda combine -> bf16 Y (overlays dead Qp)
    combine_kernel<<<S_LEN * DIM / 256, 256, 0, stream>>>(Ao, lp, Yb);

    // 5. MFMA output projection -> fp32 out
    gemm_out<<<dim3(DIM/64, S_LEN/64), 256, 0, stream>>>(Yb, Wob, out);
}